// Round 9
// baseline (31666.904 us; speedup 1.0000x reference)
//
#include <hip/hip_runtime.h>

// Problem constants (from reference)
#define BB    2048
#define TT    100
#define CC    8
#define HD    64
#define HHD   128
#define OO    10
#define MROWS 8      // batch rows per block; grid = 256 blocks = 1 block/CU
#define NTHR  1024   // 16 waves in ONE workgroup -> 4 waves/SIMD co-resident

__device__ __forceinline__ float fast_tanh(float x) {
  float e = __expf(2.0f * x);
  return 1.0f - 2.0f / (e + 1.0f);
}

__global__ void zero_out_k(float* o) {
  if (threadIdx.x < 2) o[threadIdx.x] = 0.0f;
}

// Hidden layer phase: wave (q8 = k-slice 0..7, rh = row-half 0..1).
// k in [16q8,16q8+16), rows [4rh,4rh+4), lane cols (l, l+64).
// Weights streamed from L2 in phase-local regs; relu applied on read.
// Live ~80 regs -> fits the 128-VGPR budget (proven spill-free in r6/r7).
__device__ __forceinline__ void hidden_phase(const float* __restrict__ Wg,
                                             const float (*pin)[HHD],
                                             float (*pout)[HHD],
                                             int l, int q8, int rb) {
  const int kb = 16 * q8;
  float wx[16], wy[16];
#pragma unroll
  for (int j = 0; j < 16; ++j) {
    const float* wr = Wg + (kb + j) * HHD;
    wx[j] = wr[l];                          // 256B coalesced per wave
    wy[j] = wr[l + 64];
  }
#pragma unroll
  for (int rr = 0; rr < 4; ++rr) {
    const float* pr = &pin[rb + rr][kb];
    const float4 h0 = *(const float4*)(pr);       // wave-uniform -> broadcast
    const float4 h1 = *(const float4*)(pr + 4);
    const float4 h2 = *(const float4*)(pr + 8);
    const float4 h3 = *(const float4*)(pr + 12);
    const float hk[16] = {
      fmaxf(h0.x,0.f), fmaxf(h0.y,0.f), fmaxf(h0.z,0.f), fmaxf(h0.w,0.f),
      fmaxf(h1.x,0.f), fmaxf(h1.y,0.f), fmaxf(h1.z,0.f), fmaxf(h1.w,0.f),
      fmaxf(h2.x,0.f), fmaxf(h2.y,0.f), fmaxf(h2.z,0.f), fmaxf(h2.w,0.f),
      fmaxf(h3.x,0.f), fmaxf(h3.y,0.f), fmaxf(h3.z,0.f), fmaxf(h3.w,0.f) };
    float a0 = 0.f, a1 = 0.f;
#pragma unroll
    for (int k = 0; k < 16; ++k) {
      a0 = fmaf(hk[k], wx[k], a0);
      a1 = fmaf(hk[k], wy[k], a1);
    }
    atomicAdd(&pout[rb + rr][l],      a0);  // ds_add_f32, 2 lanes/bank = free
    atomicAdd(&pout[rb + rr][l + 64], a1);
  }
}

__attribute__((amdgpu_waves_per_eu(4, 4)))   // pin 4 waves/EU -> 128-VGPR budget
__global__ void __launch_bounds__(NTHR)
cde_main(const float* __restrict__ coeffs, const int* __restrict__ yy,
         const float* __restrict__ times,
         const float* __restrict__ W_init, const float* __restrict__ b_init,
         const float* __restrict__ W_in,  const float* __restrict__ b_in,
         const float* __restrict__ W_h,   const float* __restrict__ b_h,
         const float* __restrict__ W_out, const float* __restrict__ b_out,
         const float* __restrict__ W_read,const float* __restrict__ b_read,
         float* __restrict__ out)
{
  __shared__ float sZs[MROWS][HD];        // 2KB   stage-input z
  __shared__ float pA [MROWS][HHD];       // 4KB   bias-primed partials, layer A
  __shared__ float p1 [MROWS][HHD];       // 4KB   hidden1
  __shared__ float p2 [MROWS][HHD];       // 4KB   hidden2
  __shared__ float pB [MROWS][576];       // 18KB  big layer, addr = col + (col>>3)
  __shared__ float sDx[MROWS][CC];
  __shared__ float sLog[MROWS][OO];

  const int t    = threadIdx.x;
  const int wv   = t >> 6;        // wave id 0..15
  const int l    = t & 63;        // lane
  const int q8   = wv & 7;        // k-slice id
  const int rh   = wv >> 3;       // row-half (P1-P3) / col-half (P4)
  const int rb   = 4 * rh;        // row base for P1-P3
  const int row0 = blockIdx.x * MROWS;

  // tiny persistent scalars
  const float bA  = b_in[t & 127];
  const float bH1 = b_h[t & 127];
  const float bH2 = b_h[HHD + (t & 127)];

  // ---- z0 ; waves 0..7 own (row wv, h=l) RK state ----
  float z0 = 0.f, kacc = 0.f;
  if (wv < MROWS) {
    const float* cf = coeffs + (size_t)(row0 + wv) * (TT*CC);
    float a = b_init[l];
#pragma unroll
    for (int c = 0; c < CC; ++c) a = fmaf(cf[c], W_init[c*HD + l], a);
    z0 = a;
    sZs[wv][l] = a;
  }

  // ---- prime partial buffers with bias ----
  ((float*)pA)[t] = bA;
  ((float*)p1)[t] = bH1;
  ((float*)p2)[t] = bH2;
  if (t < 512) {
    const int r = t >> 6, ll = t & 63;
    const float4 b0 = *(const float4*)(b_out + 8*ll);
    const float4 b1 = *(const float4*)(b_out + 8*ll + 4);
    float* pr = &pB[r][9*ll];
    pr[0]=b0.x; pr[1]=b0.y; pr[2]=b0.z; pr[3]=b0.w;
    pr[4]=b1.x; pr[5]=b1.y; pr[6]=b1.z; pr[7]=b1.w;
  }
  __syncthreads();

#pragma unroll 1
  for (int step = 0; step < TT-1; ++step) {
    const float dti = times[step+1] - times[step];
    if (t < MROWS * CC) {   // written here; P5 readers barrier-separated both ways
      const int r = t >> 3, c = t & 7;
      const float* cf = coeffs + (size_t)(row0 + r)*(TT*CC) + step*CC + c;
      sDx[r][c] = (cf[CC] - cf[0]) / dti;
    }

#pragma unroll 1
    for (int s = 0; s < 4; ++s) {
      // ---- P1: layer A. k in [8q8,8q8+8), rows [rb,rb+4), cols (l,l+64) ----
      {
        const int kb = 8 * q8;
        float wx[8], wy[8];
#pragma unroll
        for (int j = 0; j < 8; ++j) {
          const float* wr = W_in + (kb + j) * HHD;
          wx[j] = wr[l];
          wy[j] = wr[l + 64];
        }
#pragma unroll
        for (int rr = 0; rr < 4; ++rr) {
          const int r = rb + rr;
          const float4 za = *(const float4*)&sZs[r][kb];       // broadcast
          const float4 zb = *(const float4*)&sZs[r][kb + 4];
          const float zk[8] = {za.x, za.y, za.z, za.w, zb.x, zb.y, zb.z, zb.w};
          float a0 = 0.f, a1 = 0.f;
#pragma unroll
          for (int k = 0; k < 8; ++k) {
            a0 = fmaf(zk[k], wx[k], a0);
            a1 = fmaf(zk[k], wy[k], a1);
          }
          atomicAdd(&pA[r][l],      a0);
          atomicAdd(&pA[r][l + 64], a1);
        }
      }
      __syncthreads();
      // ---- P2: hidden1 (reads pA, relu inline) ----
      hidden_phase(W_h, pA, p1, l, q8, rb);
      __syncthreads();
      // ---- P3: hidden2 (reads p1) + re-prime pA ----
      hidden_phase(W_h + HHD*HHD, p1, p2, l, q8, rb);
      ((float*)pA)[t] = bA;
      __syncthreads();
      // ---- P4: big layer. k in [16q8,16q8+16), col-half rh, lane cols colb..+3.
      //      + re-prime p1 ----
      {
        const int kb   = 16 * q8;
        const int colb = 256 * rh + 4 * l;
        float acc[MROWS][4];
#pragma unroll
        for (int r = 0; r < MROWS; ++r)
#pragma unroll
          for (int c = 0; c < 4; ++c) acc[r][c] = 0.f;

        const float* wp = W_out + (size_t)kb * (HD*CC) + colb;
#pragma unroll
        for (int kc = 0; kc < 4; ++kc) {      // 4 chunks of 4 k
          float4 w4[4];                        // 16 regs, chunk-local
#pragma unroll
          for (int j = 0; j < 4; ++j)
            w4[j] = *(const float4*)(wp + (4*kc + j)*(HD*CC));   // 1KB/wave coalesced
#pragma unroll
          for (int r = 0; r < MROWS; ++r) {
            const float4 hv = *(const float4*)&p2[r][kb + 4*kc];   // broadcast
            const float hf[4] = { fmaxf(hv.x,0.f), fmaxf(hv.y,0.f),
                                  fmaxf(hv.z,0.f), fmaxf(hv.w,0.f) };
#pragma unroll
            for (int j = 0; j < 4; ++j) {
              acc[r][0] = fmaf(hf[j], w4[j].x, acc[r][0]);
              acc[r][1] = fmaf(hf[j], w4[j].y, acc[r][1]);
              acc[r][2] = fmaf(hf[j], w4[j].z, acc[r][2]);
              acc[r][3] = fmaf(hf[j], w4[j].w, acc[r][3]);
            }
          }
        }
#pragma unroll
        for (int r = 0; r < MROWS; ++r)
#pragma unroll
          for (int c = 0; c < 4; ++c) {
            const int col = colb + c;
            atomicAdd(&pB[r][col + (col >> 3)], acc[r][c]);
          }
        ((float*)p1)[t] = bH1;
      }
      __syncthreads();
      // ---- P5: epilogue (waves 0..7) + re-prime pB row + re-prime p2 (all) ----
      if (wv < MROWS) {
        float* pr = &pB[wv][9*l];
        const float u0 = pr[0], u1 = pr[1], u2 = pr[2], u3 = pr[3];
        const float u4 = pr[4], u5 = pr[5], u6 = pr[6], u7 = pr[7];
        const float4 d0 = *(const float4*)&sDx[wv][0];    // broadcast
        const float4 d1 = *(const float4*)&sDx[wv][4];
        float g = fast_tanh(u0)*d0.x + fast_tanh(u1)*d0.y
                + fast_tanh(u2)*d0.z + fast_tanh(u3)*d0.w
                + fast_tanh(u4)*d1.x + fast_tanh(u5)*d1.y
                + fast_tanh(u6)*d1.z + fast_tanh(u7)*d1.w;
        if (s == 0)      kacc = g;
        else if (s == 3) kacc += g;
        else             kacc += 2.0f * g;
        float zs;
        if (s == 3) {
          z0 = z0 + dti * (1.0f/6.0f) * kacc;
          zs = z0;
        } else {
          zs = z0 + ((s == 2) ? dti : 0.5f * dti) * g;
        }
        sZs[wv][l] = zs;
        const float4 b0 = *(const float4*)(b_out + 8*l);     // L1-hot
        const float4 b1 = *(const float4*)(b_out + 8*l + 4);
        pr[0]=b0.x; pr[1]=b0.y; pr[2]=b0.z; pr[3]=b0.w;
        pr[4]=b1.x; pr[5]=b1.y; pr[6]=b1.z; pr[7]=b1.w;
      }
      ((float*)p2)[t] = bH2;
      __syncthreads();
    } // stages
  }   // steps

  // ---- readout: logits = zT @ W_read + b_read ; loss + accuracy ----
  if (t < MROWS * OO) {
    const int r = t / OO, o = t % OO;
    float a = b_read[o];
#pragma unroll 8
    for (int k = 0; k < HD; ++k) a = fmaf(sZs[r][k], W_read[k*OO + o], a);
    sLog[r][o] = a;
  }
  __syncthreads();
  if (t < 64) {
    float lv = 0.f, cv = 0.f;
    if (t < MROWS) {
      const int r = t;
      float mx = sLog[r][0]; int am = 0;
#pragma unroll
      for (int o = 1; o < OO; ++o) { const float v = sLog[r][o]; if (v > mx) { mx = v; am = o; } }
      float se = 0.f;
#pragma unroll
      for (int o = 0; o < OO; ++o) se += expf(sLog[r][o] - mx);
      const float lse = mx + logf(se);
      const int yr = yy[row0 + r];
      lv = (lse - sLog[r][yr]) * (1.0f / (float)BB);
      cv = (am == yr) ? 1.0f : 0.0f;
    }
    lv += __shfl_xor(lv, 1); lv += __shfl_xor(lv, 2); lv += __shfl_xor(lv, 4);
    cv += __shfl_xor(cv, 1); cv += __shfl_xor(cv, 2); cv += __shfl_xor(cv, 4);
    if (t == 0) { atomicAdd(&out[0], lv); atomicAdd(&out[1], cv); }
  }
}

extern "C" void kernel_launch(void* const* d_in, const int* in_sizes, int n_in,
                              void* d_out, int out_size, void* d_ws, size_t ws_size,
                              hipStream_t stream) {
  const float* coeffs = (const float*)d_in[0];
  const int*   y      = (const int*)  d_in[1];
  const float* times  = (const float*)d_in[2];
  const float* W_init = (const float*)d_in[3];
  const float* b_init = (const float*)d_in[4];
  const float* W_in   = (const float*)d_in[5];
  const float* b_in   = (const float*)d_in[6];
  const float* W_h    = (const float*)d_in[7];
  const float* b_h    = (const float*)d_in[8];
  const float* W_out  = (const float*)d_in[9];
  const float* b_out  = (const float*)d_in[10];
  const float* W_read = (const float*)d_in[11];
  const float* b_read = (const float*)d_in[12];
  float* out = (float*)d_out;

  zero_out_k<<<1, 64, 0, stream>>>(out);   // d_out is poisoned 0xAA before every replay
  cde_main<<<BB/MROWS, NTHR, 0, stream>>>(coeffs, y, times, W_init, b_init,
                                          W_in, b_in, W_h, b_h, W_out, b_out,
                                          W_read, b_read, out);
}

// Round 10
// 24812.379 us; speedup vs baseline: 1.2763x; 1.2763x over previous
//
#include <hip/hip_runtime.h>

// Problem constants (from reference)
#define BB    2048
#define TT    100
#define CC    8
#define HD    64
#define HHD   128
#define OO    10
#define MROWS 8      // batch rows per block; grid = 256 blocks = 1 block/CU
#define NTHR  1024   // 16 waves in ONE workgroup -> 4 waves/SIMD co-resident
                     // (1024-thr WG pins VGPR budget to 64 -> ALL phases sized <=~45 live)

__device__ __forceinline__ float fast_tanh(float x) {
  float e = __expf(2.0f * x);
  return 1.0f - 2.0f / (e + 1.0f);
}

__global__ void zero_out_k(float* o) {
  if (threadIdx.x < 2) o[threadIdx.x] = 0.0f;
}

// Hidden layer phase sized for 64-VGPR budget:
// wave = (q8 = k-slice 0..7 -> k in [16q8,16q8+16), rh -> rows [4rh,4rh+4)),
// lane owns cols (l, l+64). Weights streamed from L2 in 8-k chunks (16 live regs).
__device__ __forceinline__ void hidden_phase(const float* __restrict__ Wg,
                                             const float (*pin)[HHD],
                                             float (*pout)[HHD],
                                             int l, int q8, int rb) {
  const int kb = 16 * q8;
  float a0[4] = {0.f,0.f,0.f,0.f};
  float a1[4] = {0.f,0.f,0.f,0.f};
#pragma unroll
  for (int h = 0; h < 2; ++h) {              // two 8-k chunks
    float wx[8], wy[8];                       // 16 regs, chunk-local
#pragma unroll
    for (int j = 0; j < 8; ++j) {
      const float* wr = Wg + (kb + 8*h + j) * HHD;
      wx[j] = wr[l];                          // 256B coalesced per wave
      wy[j] = wr[l + 64];
    }
#pragma unroll
    for (int rr = 0; rr < 4; ++rr) {
      const float* pr = &pin[rb + rr][kb + 8*h];
      const float4 h0 = *(const float4*)(pr);       // wave-uniform -> broadcast
      const float4 h1 = *(const float4*)(pr + 4);
      const float hk[8] = {
        fmaxf(h0.x,0.f), fmaxf(h0.y,0.f), fmaxf(h0.z,0.f), fmaxf(h0.w,0.f),
        fmaxf(h1.x,0.f), fmaxf(h1.y,0.f), fmaxf(h1.z,0.f), fmaxf(h1.w,0.f) };
#pragma unroll
      for (int k = 0; k < 8; ++k) {
        a0[rr] = fmaf(hk[k], wx[k], a0[rr]);
        a1[rr] = fmaf(hk[k], wy[k], a1[rr]);
      }
    }
  }
#pragma unroll
  for (int rr = 0; rr < 4; ++rr) {           // ds_add_f32, 2 lanes/bank = free
    atomicAdd(&pout[rb + rr][l],      a0[rr]);
    atomicAdd(&pout[rb + rr][l + 64], a1[rr]);
  }
}

__global__ void __launch_bounds__(NTHR)
cde_main(const float* __restrict__ coeffs, const int* __restrict__ yy,
         const float* __restrict__ times,
         const float* __restrict__ W_init, const float* __restrict__ b_init,
         const float* __restrict__ W_in,  const float* __restrict__ b_in,
         const float* __restrict__ W_h,   const float* __restrict__ b_h,
         const float* __restrict__ W_out, const float* __restrict__ b_out,
         const float* __restrict__ W_read,const float* __restrict__ b_read,
         float* __restrict__ out)
{
  __shared__ float sZs[MROWS][HD];        // 2KB   stage-input z
  __shared__ float pA [MROWS][HHD];       // 4KB   bias-primed partials, layer A
  __shared__ float p1 [MROWS][HHD];       // 4KB   hidden1
  __shared__ float p2 [MROWS][HHD];       // 4KB   hidden2
  __shared__ float pB [MROWS][576];       // 18KB  big layer, addr = col + (col>>3)
  __shared__ float sDx[MROWS][CC];
  __shared__ float sLog[MROWS][OO];

  const int t    = threadIdx.x;
  const int wv   = t >> 6;        // wave id 0..15
  const int l    = t & 63;        // lane
  const int q8   = wv & 7;        // k-slice id (P1-P3)
  const int rb   = 4 * (wv >> 3); // row base (P1-P3)
  const int row0 = blockIdx.x * MROWS;

  // tiny persistent scalars
  const float bA  = b_in[t & 127];
  const float bH1 = b_h[t & 127];
  const float bH2 = b_h[HHD + (t & 127)];

  // ---- z0 ; waves 0..7 own (row wv, h=l) RK state ----
  float z0 = 0.f, kacc = 0.f;
  if (wv < MROWS) {
    const float* cf = coeffs + (size_t)(row0 + wv) * (TT*CC);
    float a = b_init[l];
#pragma unroll
    for (int c = 0; c < CC; ++c) a = fmaf(cf[c], W_init[c*HD + l], a);
    z0 = a;
    sZs[wv][l] = a;
  }

  // ---- prime partial buffers with bias ----
  ((float*)pA)[t] = bA;
  ((float*)p1)[t] = bH1;
  ((float*)p2)[t] = bH2;
  if (t < 512) {
    const int r = t >> 6, ll = t & 63;
    const float4 b0 = *(const float4*)(b_out + 8*ll);
    const float4 b1 = *(const float4*)(b_out + 8*ll + 4);
    float* pr = &pB[r][9*ll];
    pr[0]=b0.x; pr[1]=b0.y; pr[2]=b0.z; pr[3]=b0.w;
    pr[4]=b1.x; pr[5]=b1.y; pr[6]=b1.z; pr[7]=b1.w;
  }
  __syncthreads();

#pragma unroll 1
  for (int step = 0; step < TT-1; ++step) {
    const float dti = times[step+1] - times[step];
    if (t < MROWS * CC) {   // P5 readers barrier-separated both directions
      const int r = t >> 3, c = t & 7;
      const float* cf = coeffs + (size_t)(row0 + r)*(TT*CC) + step*CC + c;
      sDx[r][c] = (cf[CC] - cf[0]) / dti;
    }

#pragma unroll 1
    for (int s = 0; s < 4; ++s) {
      // ---- P1: layer A. k in [8q8,8q8+8), rows [rb,rb+4), cols (l,l+64) ----
      {
        const int kb = 8 * q8;
        float wx[8], wy[8];
#pragma unroll
        for (int j = 0; j < 8; ++j) {
          const float* wr = W_in + (kb + j) * HHD;
          wx[j] = wr[l];
          wy[j] = wr[l + 64];
        }
#pragma unroll
        for (int rr = 0; rr < 4; ++rr) {
          const int r = rb + rr;
          const float4 za = *(const float4*)&sZs[r][kb];       // broadcast
          const float4 zb = *(const float4*)&sZs[r][kb + 4];
          const float zk[8] = {za.x, za.y, za.z, za.w, zb.x, zb.y, zb.z, zb.w};
          float a0 = 0.f, a1 = 0.f;
#pragma unroll
          for (int k = 0; k < 8; ++k) {
            a0 = fmaf(zk[k], wx[k], a0);
            a1 = fmaf(zk[k], wy[k], a1);
          }
          atomicAdd(&pA[r][l],      a0);
          atomicAdd(&pA[r][l + 64], a1);
        }
      }
      __syncthreads();
      // ---- P2: hidden1 (reads pA, relu inline) ----
      hidden_phase(W_h, pA, p1, l, q8, rb);
      __syncthreads();
      // ---- P3: hidden2 (reads p1) + re-prime pA ----
      hidden_phase(W_h + HHD*HHD, p1, p2, l, q8, rb);
      ((float*)pA)[t] = bA;
      __syncthreads();
      // ---- P4: big layer. wave = (kq = wv&3 -> k in [32kq,32kq+32),
      //      cq = wv>>2 -> cols [128cq,128cq+128)); lane cols (cb+l, cb+64+l).
      //      acc0/acc1 = 16 regs; 4-k weight chunks = 8 regs. + re-prime p1 ----
      {
        const int kb = 32 * (wv & 3);
        const int cb = 128 * (wv >> 2);
        float acc0[MROWS], acc1[MROWS];
#pragma unroll
        for (int r = 0; r < MROWS; ++r) { acc0[r] = 0.f; acc1[r] = 0.f; }

        const float* wp = W_out + (size_t)kb * (HD*CC) + cb + l;
#pragma unroll
        for (int kc = 0; kc < 8; ++kc) {      // 8 chunks of 4 k
          float w0[4], w1[4];                  // 8 regs, chunk-local
#pragma unroll
          for (int j = 0; j < 4; ++j) {
            w0[j] = wp[(4*kc + j)*(HD*CC)];        // 256B coalesced
            w1[j] = wp[(4*kc + j)*(HD*CC) + 64];
          }
#pragma unroll
          for (int r = 0; r < MROWS; ++r) {
            const float4 hv = *(const float4*)&p2[r][kb + 4*kc];   // broadcast
            const float hf[4] = { fmaxf(hv.x,0.f), fmaxf(hv.y,0.f),
                                  fmaxf(hv.z,0.f), fmaxf(hv.w,0.f) };
#pragma unroll
            for (int j = 0; j < 4; ++j) {
              acc0[r] = fmaf(hf[j], w0[j], acc0[r]);
              acc1[r] = fmaf(hf[j], w1[j], acc1[r]);
            }
          }
        }
        const int c0 = cb + l, c1 = cb + 64 + l;
        const int a0i = c0 + (c0 >> 3), a1i = c1 + (c1 >> 3);
#pragma unroll
        for (int r = 0; r < MROWS; ++r) {
          atomicAdd(&pB[r][a0i], acc0[r]);
          atomicAdd(&pB[r][a1i], acc1[r]);
        }
        ((float*)p1)[t] = bH1;
      }
      __syncthreads();
      // ---- P5: epilogue (waves 0..7) + re-prime pB row + re-prime p2 (all) ----
      if (wv < MROWS) {
        float* pr = &pB[wv][9*l];             // cols 8l..8l+7, conflict-free
        const float u0 = pr[0], u1 = pr[1], u2 = pr[2], u3 = pr[3];
        const float u4 = pr[4], u5 = pr[5], u6 = pr[6], u7 = pr[7];
        const float4 d0 = *(const float4*)&sDx[wv][0];    // broadcast
        const float4 d1 = *(const float4*)&sDx[wv][4];
        float g = fast_tanh(u0)*d0.x + fast_tanh(u1)*d0.y
                + fast_tanh(u2)*d0.z + fast_tanh(u3)*d0.w
                + fast_tanh(u4)*d1.x + fast_tanh(u5)*d1.y
                + fast_tanh(u6)*d1.z + fast_tanh(u7)*d1.w;
        if (s == 0)      kacc = g;
        else if (s == 3) kacc += g;
        else             kacc += 2.0f * g;
        float zs;
        if (s == 3) {
          z0 = z0 + dti * (1.0f/6.0f) * kacc;
          zs = z0;
        } else {
          zs = z0 + ((s == 2) ? dti : 0.5f * dti) * g;
        }
        sZs[wv][l] = zs;
        const float4 b0 = *(const float4*)(b_out + 8*l);   // L1-hot
        const float4 b1 = *(const float4*)(b_out + 8*l + 4);
        pr[0]=b0.x; pr[1]=b0.y; pr[2]=b0.z; pr[3]=b0.w;
        pr[4]=b1.x; pr[5]=b1.y; pr[6]=b1.z; pr[7]=b1.w;
      }
      ((float*)p2)[t] = bH2;
      __syncthreads();
    } // stages
  }   // steps

  // ---- readout: logits = zT @ W_read + b_read ; loss + accuracy ----
  if (t < MROWS * OO) {
    const int r = t / OO, o = t % OO;
    float a = b_read[o];
#pragma unroll 8
    for (int k = 0; k < HD; ++k) a = fmaf(sZs[r][k], W_read[k*OO + o], a);
    sLog[r][o] = a;
  }
  __syncthreads();
  if (t < 64) {
    float lv = 0.f, cv = 0.f;
    if (t < MROWS) {
      const int r = t;
      float mx = sLog[r][0]; int am = 0;
#pragma unroll
      for (int o = 1; o < OO; ++o) { const float v = sLog[r][o]; if (v > mx) { mx = v; am = o; } }
      float se = 0.f;
#pragma unroll
      for (int o = 0; o < OO; ++o) se += expf(sLog[r][o] - mx);
      const float lse = mx + logf(se);
      const int yr = yy[row0 + r];
      lv = (lse - sLog[r][yr]) * (1.0f / (float)BB);
      cv = (am == yr) ? 1.0f : 0.0f;
    }
    lv += __shfl_xor(lv, 1); lv += __shfl_xor(lv, 2); lv += __shfl_xor(lv, 4);
    cv += __shfl_xor(cv, 1); cv += __shfl_xor(cv, 2); cv += __shfl_xor(cv, 4);
    if (t == 0) { atomicAdd(&out[0], lv); atomicAdd(&out[1], cv); }
  }
}

extern "C" void kernel_launch(void* const* d_in, const int* in_sizes, int n_in,
                              void* d_out, int out_size, void* d_ws, size_t ws_size,
                              hipStream_t stream) {
  const float* coeffs = (const float*)d_in[0];
  const int*   y      = (const int*)  d_in[1];
  const float* times  = (const float*)d_in[2];
  const float* W_init = (const float*)d_in[3];
  const float* b_init = (const float*)d_in[4];
  const float* W_in   = (const float*)d_in[5];
  const float* b_in   = (const float*)d_in[6];
  const float* W_h    = (const float*)d_in[7];
  const float* b_h    = (const float*)d_in[8];
  const float* W_out  = (const float*)d_in[9];
  const float* b_out  = (const float*)d_in[10];
  const float* W_read = (const float*)d_in[11];
  const float* b_read = (const float*)d_in[12];
  float* out = (float*)d_out;

  zero_out_k<<<1, 64, 0, stream>>>(out);   // d_out is poisoned 0xAA before every replay
  cde_main<<<BB/MROWS, NTHR, 0, stream>>>(coeffs, y, times, W_init, b_init,
                                          W_in, b_in, W_h, b_h, W_out, b_out,
                                          W_read, b_read, out);
}